// Round 5
// baseline (86.216 us; speedup 1.0000x reference)
//
#include <hip/hip_runtime.h>

#define T_N 256
#define O_N 64
#define K_N 16
#define HW_N (224 * 224)      // 50176
#define DM 768
#define DO 2048
#define OMEGA_F 1e-6f

// ---- proj decomposition: column-tiles x K-segments, atomic split-K ----
#define PCOLS 64
#define DSEG 64                     // d's per proj block
#define NSEG (DM / DSEG)            // 12
#define NT_O (DO / PCOLS)           // 32 col-tiles (obj proj)
#define NT_F (DM / PCOLS)           // 12 col-tiles (frame proj)
#define NB_PROJ ((NT_O + NT_F) * NSEG)   // 528
#define SUBB 4
#define NB_HIST (T_N * SUBB)        // 1024

// ---- fusedB decomposition: flat grid-stride obj + frame tail blocks ----
#define NB_OBJ 2048
#define OBJ_TOTAL4 (T_N * O_N * (DO / 4))      // 8,388,608 float4s
#define OBJ_STRIDE (NB_OBJ * 256)              // 524,288
#define OBJ_ITERS (OBJ_TOTAL4 / OBJ_STRIDE)    // 16 exactly

// ============ Kernel A: proj blocks [0..527] + histogram blocks [528..1551]
// (unchanged from R4 — ~12 us, overlapped streams)
__global__ __launch_bounds__(256) void fusedA(const float* __restrict__ me,
                                              const float* __restrict__ Wo, const float* __restrict__ bo,
                                              const float* __restrict__ Wf, const float* __restrict__ bf,
                                              const int* __restrict__ masks,
                                              float* __restrict__ proj_obj, float* __restrict__ proj_frame,
                                              float* __restrict__ counts_partial) {
    __shared__ char smem[20480];
    const int b = blockIdx.x;
    const int tid = threadIdx.x;

    if (b < NB_PROJ) {
        float (*partial)[K_N][PCOLS] = (float (*)[K_N][PCOLS])smem;          // [4][16][64]
        float* me_s = (float*)(smem + 4 * K_N * PCOLS * sizeof(float));      // [16][64]
        const int tile = b / NSEG, seg = b - tile * NSEG;
        const float* W; const float* bias; float* out; int ld; int j0;
        if (tile < NT_O) { W = Wo; bias = bo; out = proj_obj;   ld = DO; j0 = tile * PCOLS; }
        else             { W = Wf; bias = bf; out = proj_frame; ld = DM; j0 = (tile - NT_O) * PCOLS; }
        const int d0 = seg * DSEG;

        for (int i = tid; i < K_N * DSEG; i += 256) {
            int k = i >> 6, dd = i & 63;
            me_s[i] = me[k * DM + d0 + dd];
        }
        __syncthreads();

        const int jj = tid & (PCOLS - 1);
        const int s  = tid >> 6;            // wave id 0..3
        const int j  = j0 + jj;
        const int db = s * 16;

        float acc[K_N];
        #pragma unroll
        for (int k = 0; k < K_N; ++k) acc[k] = 0.f;

        #pragma unroll
        for (int dd = 0; dd < 16; ++dd) {
            float w = W[(size_t)(d0 + db + dd) * ld + j];      // coalesced
            #pragma unroll
            for (int k = 0; k < K_N; ++k)
                acc[k] += me_s[k * DSEG + db + dd] * w;        // LDS broadcast
        }
        #pragma unroll
        for (int k = 0; k < K_N; ++k) partial[s][k][jj] = acc[k];
        __syncthreads();

        for (int o = tid; o < K_N * PCOLS; o += 256) {
            int k = o >> 6, c = o & 63;
            float v = partial[0][k][c] + partial[1][k][c]
                    + partial[2][k][c] + partial[3][k][c];
            if (seg == NSEG - 1) v += bias[j0 + c];
            atomicAdd(&out[k * ld + j0 + c], v);
        }
    } else {
        int* bins = (int*)smem;                                  // 256*17 ints
        int (*partial2)[17] = (int (*)[17])(smem + 256 * 17 * 4);
        const int hb = b - NB_PROJ;
        const int t = hb >> 2, sub = hb & 3;
        int* my = &bins[tid * 17];
        #pragma unroll
        for (int i = 0; i < 17; ++i) my[i] = 0;

        const int4* p = (const int4*)(masks + (size_t)t * HW_N);
        const int n4 = HW_N / 4;          // 12544
        const int chunk = n4 / SUBB;      // 3136
        const int end = (sub + 1) * chunk;
        for (int i = sub * chunk + tid; i < end; i += 256) {
            int4 v = p[i];
            my[v.x]++; my[v.y]++; my[v.z]++; my[v.w]++;
        }
        __syncthreads();
        const int bcol = tid & 15, rg = tid >> 4;
        int ssum = 0;
        #pragma unroll
        for (int r = 0; r < 16; ++r) ssum += bins[(rg * 16 + r) * 17 + (bcol + 1)];
        partial2[rg][bcol] = ssum;
        __syncthreads();
        if (tid < 16) {
            int s = 0;
            #pragma unroll
            for (int r = 0; r < 16; ++r) s += partial2[r][tid];
            counts_partial[((size_t)sub * T_N + t) * K_N + tid] = (float)s;
        }
    }
}

// ============ Kernel B: flat grid-stride obj injection [0..2047] + frame blocks [2048..2303]
__global__ __launch_bounds__(256) void fusedB(const float* __restrict__ obj_feat,
                                              const int* __restrict__ obj_entity,
                                              const float* __restrict__ proj_obj,
                                              const float* __restrict__ frame_feat,
                                              const float* __restrict__ counts_partial,
                                              const float* __restrict__ proj_frame,
                                              const float* __restrict__ gamma,
                                              float* __restrict__ obj_out,
                                              float* __restrict__ frame_out) {
    __shared__ float c[K_N];
    const int b = blockIdx.x;
    const float g = gamma[0];

    if (b < NB_OBJ) {
        // ---- obj: branchless flat float4 stream, exactly 16 iters/thread
        const float4* __restrict__ src = (const float4*)obj_feat;
        const float4* __restrict__ prj = (const float4*)proj_obj;   // [16][512]
        float4* __restrict__ dst = (float4*)obj_out;
        const int base = b * 256 + threadIdx.x;
        #pragma unroll 4
        for (int it = 0; it < OBJ_ITERS; ++it) {
            const int idx = base + it * OBJ_STRIDE;
            const int row = idx >> 9;                // 512 float4 per row
            const int e = obj_entity[row];           // L1-hot, near-uniform per wave
            const float sc = (e > 0) ? g : 0.f;
            const int prow = (e > 0) ? (e - 1) : 0;
            float4 a = src[idx];
            float4 p = prj[prow * 512 + (idx & 511)];
            dst[idx] = make_float4(a.x + sc * p.x, a.y + sc * p.y,
                                   a.z + sc * p.z, a.w + sc * p.w);
        }
    } else {
        // ---- frame: one block per frame t
        const int t = b - NB_OBJ;
        if (threadIdx.x < K_N) {
            float s = 0.f;
            #pragma unroll
            for (int sb = 0; sb < SUBB; ++sb)
                s += counts_partial[((size_t)sb * T_N + t) * K_N + threadIdx.x];
            c[threadIdx.x] = s;
        }
        __syncthreads();
        float tot = 0.f;
        #pragma unroll
        for (int k = 0; k < K_N; ++k) tot += c[k];
        const float inv = g / (OMEGA_F + tot);
        for (int j = threadIdx.x; j < DM; j += 256) {
            float acc = 0.f;
            #pragma unroll
            for (int k = 0; k < K_N; ++k) acc += c[k] * proj_frame[k * DM + j];
            frame_out[t * DM + j] = frame_feat[t * DM + j] + acc * inv;
        }
    }
}

extern "C" void kernel_launch(void* const* d_in, const int* in_sizes, int n_in,
                              void* d_out, int out_size, void* d_ws, size_t ws_size,
                              hipStream_t stream) {
    const float* obj_feat   = (const float*)d_in[0];   // [T,O,DO]
    const float* frame_feat = (const float*)d_in[1];   // [T,DM]
    const float* me         = (const float*)d_in[2];   // [K,DM]
    const int*   obj_entity = (const int*)d_in[3];     // [T,O]
    const int*   masks      = (const int*)d_in[4];     // [T,H,W]
    const float* Wo         = (const float*)d_in[5];   // [DM,DO]
    const float* bo         = (const float*)d_in[6];   // [DO]
    const float* Wf         = (const float*)d_in[7];   // [DM,DM]
    const float* bf         = (const float*)d_in[8];   // [DM]
    const float* gamma      = (const float*)d_in[9];   // scalar

    float* obj_out   = (float*)d_out;                          // [T,O,DO]
    float* frame_out = (float*)d_out + (size_t)T_N * O_N * DO; // [T,DM]

    float* ws = (float*)d_ws;
    float* proj_obj       = ws;                  // 16*2048 = 32768 floats
    float* proj_frame     = ws + 32768;          // 16*768  = 12288 floats
    float* counts_partial = ws + 32768 + 12288;  // 4*256*16 = 16384 floats

    // zero the atomic split-K accumulators (capture-legal memset node)
    hipMemsetAsync(ws, 0, (size_t)(32768 + 12288) * sizeof(float), stream);

    fusedA<<<NB_PROJ + NB_HIST, 256, 0, stream>>>(
        me, Wo, bo, Wf, bf, masks, proj_obj, proj_frame, counts_partial);
    fusedB<<<NB_OBJ + T_N, 256, 0, stream>>>(
        obj_feat, obj_entity, proj_obj, frame_feat, counts_partial, proj_frame,
        gamma, obj_out, frame_out);
}

// Round 6
// 79.306 us; speedup vs baseline: 1.0871x; 1.0871x over previous
//
#include <hip/hip_runtime.h>

#define T_N 256
#define O_N 64
#define K_N 16
#define HW_N (224 * 224)      // 50176
#define DM 768
#define DO 2048
#define OMEGA_F 1e-6f

// ---- proj decomposition: column-tiles x K-segments, atomic split-K ----
#define PCOLS 64
#define DSEG 64                     // d's per proj block
#define NSEG (DM / DSEG)            // 12
#define NT_O (DO / PCOLS)           // 32 col-tiles (obj proj)
#define NT_F (DM / PCOLS)           // 12 col-tiles (frame proj)
#define NB_PROJ ((NT_O + NT_F) * NSEG)   // 528
#define SUBB 4
#define NB_HIST (T_N * SUBB)        // 1024

// ---- fusedB: one wave per obj row; 4 rows per block ----
#define NB_OBJ (T_N * O_N / 4)      // 4096

// ============ Kernel A: proj blocks [0..527] + histogram blocks [528..1551]
// (unchanged from R4 — ~9 us including memset, overlapped streams)
__global__ __launch_bounds__(256) void fusedA(const float* __restrict__ me,
                                              const float* __restrict__ Wo, const float* __restrict__ bo,
                                              const float* __restrict__ Wf, const float* __restrict__ bf,
                                              const int* __restrict__ masks,
                                              float* __restrict__ proj_obj, float* __restrict__ proj_frame,
                                              float* __restrict__ counts_partial) {
    __shared__ char smem[20480];
    const int b = blockIdx.x;
    const int tid = threadIdx.x;

    if (b < NB_PROJ) {
        float (*partial)[K_N][PCOLS] = (float (*)[K_N][PCOLS])smem;          // [4][16][64]
        float* me_s = (float*)(smem + 4 * K_N * PCOLS * sizeof(float));      // [16][64]
        const int tile = b / NSEG, seg = b - tile * NSEG;
        const float* W; const float* bias; float* out; int ld; int j0;
        if (tile < NT_O) { W = Wo; bias = bo; out = proj_obj;   ld = DO; j0 = tile * PCOLS; }
        else             { W = Wf; bias = bf; out = proj_frame; ld = DM; j0 = (tile - NT_O) * PCOLS; }
        const int d0 = seg * DSEG;

        for (int i = tid; i < K_N * DSEG; i += 256) {
            int k = i >> 6, dd = i & 63;
            me_s[i] = me[k * DM + d0 + dd];
        }
        __syncthreads();

        const int jj = tid & (PCOLS - 1);
        const int s  = tid >> 6;            // wave id 0..3
        const int j  = j0 + jj;
        const int db = s * 16;

        float acc[K_N];
        #pragma unroll
        for (int k = 0; k < K_N; ++k) acc[k] = 0.f;

        #pragma unroll
        for (int dd = 0; dd < 16; ++dd) {
            float w = W[(size_t)(d0 + db + dd) * ld + j];      // coalesced
            #pragma unroll
            for (int k = 0; k < K_N; ++k)
                acc[k] += me_s[k * DSEG + db + dd] * w;        // LDS broadcast
        }
        #pragma unroll
        for (int k = 0; k < K_N; ++k) partial[s][k][jj] = acc[k];
        __syncthreads();

        for (int o = tid; o < K_N * PCOLS; o += 256) {
            int k = o >> 6, c = o & 63;
            float v = partial[0][k][c] + partial[1][k][c]
                    + partial[2][k][c] + partial[3][k][c];
            if (seg == NSEG - 1) v += bias[j0 + c];
            atomicAdd(&out[k * ld + j0 + c], v);
        }
    } else {
        int* bins = (int*)smem;                                  // 256*17 ints
        int (*partial2)[17] = (int (*)[17])(smem + 256 * 17 * 4);
        const int hb = b - NB_PROJ;
        const int t = hb >> 2, sub = hb & 3;
        int* my = &bins[tid * 17];
        #pragma unroll
        for (int i = 0; i < 17; ++i) my[i] = 0;

        const int4* p = (const int4*)(masks + (size_t)t * HW_N);
        const int n4 = HW_N / 4;          // 12544
        const int chunk = n4 / SUBB;      // 3136
        const int end = (sub + 1) * chunk;
        for (int i = sub * chunk + tid; i < end; i += 256) {
            int4 v = p[i];
            my[v.x]++; my[v.y]++; my[v.z]++; my[v.w]++;
        }
        __syncthreads();
        const int bcol = tid & 15, rg = tid >> 4;
        int ssum = 0;
        #pragma unroll
        for (int r = 0; r < 16; ++r) ssum += bins[(rg * 16 + r) * 17 + (bcol + 1)];
        partial2[rg][bcol] = ssum;
        __syncthreads();
        if (tid < 16) {
            int s = 0;
            #pragma unroll
            for (int r = 0; r < 16; ++r) s += partial2[r][tid];
            counts_partial[((size_t)sub * T_N + t) * K_N + tid] = (float)s;
        }
    }
}

// ============ Kernel B: one wave per obj row (blocks 0..4095), frame blocks [4096..4351]
__global__ __launch_bounds__(256) void fusedB(const float* __restrict__ obj_feat,
                                              const int* __restrict__ obj_entity,
                                              const float* __restrict__ proj_obj,
                                              const float* __restrict__ frame_feat,
                                              const float* __restrict__ counts_partial,
                                              const float* __restrict__ proj_frame,
                                              const float* __restrict__ gamma,
                                              float* __restrict__ obj_out,
                                              float* __restrict__ frame_out) {
    __shared__ float c[K_N];
    const int b = blockIdx.x;
    const float g = gamma[0];

    if (b < NB_OBJ) {
        // ---- obj: wave w owns row b*4+w; 64 lanes x 8 float4 = one 2048-float row
        const int wave = threadIdx.x >> 6;
        const int lane = threadIdx.x & 63;
        const int row = b * 4 + wave;
        const int e = obj_entity[row];              // wave-uniform scalar load
        const float4* __restrict__ src = (const float4*)(obj_feat + (size_t)row * DO);
        float4* __restrict__ dst = (float4*)(obj_out + (size_t)row * DO);
        if (e > 0) {                                // wave-uniform branch, no divergence
            const float4* __restrict__ pr = (const float4*)(proj_obj + (size_t)(e - 1) * DO);
            float4 a[8], p[8];
            #pragma unroll
            for (int it = 0; it < 8; ++it) a[it] = src[lane + it * 64];
            #pragma unroll
            for (int it = 0; it < 8; ++it) p[it] = pr[lane + it * 64];
            #pragma unroll
            for (int it = 0; it < 8; ++it)
                dst[lane + it * 64] = make_float4(a[it].x + g * p[it].x,
                                                  a[it].y + g * p[it].y,
                                                  a[it].z + g * p[it].z,
                                                  a[it].w + g * p[it].w);
        } else {
            float4 a[8];
            #pragma unroll
            for (int it = 0; it < 8; ++it) a[it] = src[lane + it * 64];
            #pragma unroll
            for (int it = 0; it < 8; ++it) dst[lane + it * 64] = a[it];
        }
    } else {
        // ---- frame: one block per frame t
        const int t = b - NB_OBJ;
        if (threadIdx.x < K_N) {
            float s = 0.f;
            #pragma unroll
            for (int sb = 0; sb < SUBB; ++sb)
                s += counts_partial[((size_t)sb * T_N + t) * K_N + threadIdx.x];
            c[threadIdx.x] = s;
        }
        __syncthreads();
        float tot = 0.f;
        #pragma unroll
        for (int k = 0; k < K_N; ++k) tot += c[k];
        const float inv = g / (OMEGA_F + tot);
        for (int j = threadIdx.x; j < DM; j += 256) {
            float acc = 0.f;
            #pragma unroll
            for (int k = 0; k < K_N; ++k) acc += c[k] * proj_frame[k * DM + j];
            frame_out[t * DM + j] = frame_feat[t * DM + j] + acc * inv;
        }
    }
}

extern "C" void kernel_launch(void* const* d_in, const int* in_sizes, int n_in,
                              void* d_out, int out_size, void* d_ws, size_t ws_size,
                              hipStream_t stream) {
    const float* obj_feat   = (const float*)d_in[0];   // [T,O,DO]
    const float* frame_feat = (const float*)d_in[1];   // [T,DM]
    const float* me         = (const float*)d_in[2];   // [K,DM]
    const int*   obj_entity = (const int*)d_in[3];     // [T,O]
    const int*   masks      = (const int*)d_in[4];     // [T,H,W]
    const float* Wo         = (const float*)d_in[5];   // [DM,DO]
    const float* bo         = (const float*)d_in[6];   // [DO]
    const float* Wf         = (const float*)d_in[7];   // [DM,DM]
    const float* bf         = (const float*)d_in[8];   // [DM]
    const float* gamma      = (const float*)d_in[9];   // scalar

    float* obj_out   = (float*)d_out;                          // [T,O,DO]
    float* frame_out = (float*)d_out + (size_t)T_N * O_N * DO; // [T,DM]

    float* ws = (float*)d_ws;
    float* proj_obj       = ws;                  // 16*2048 = 32768 floats
    float* proj_frame     = ws + 32768;          // 16*768  = 12288 floats
    float* counts_partial = ws + 32768 + 12288;  // 4*256*16 = 16384 floats

    // zero the atomic split-K accumulators (capture-legal memset node)
    hipMemsetAsync(ws, 0, (size_t)(32768 + 12288) * sizeof(float), stream);

    fusedA<<<NB_PROJ + NB_HIST, 256, 0, stream>>>(
        me, Wo, bo, Wf, bf, masks, proj_obj, proj_frame, counts_partial);
    fusedB<<<NB_OBJ + T_N, 256, 0, stream>>>(
        obj_feat, obj_entity, proj_obj, frame_feat, counts_partial, proj_frame,
        gamma, obj_out, frame_out);
}

// Round 7
// 67.513 us; speedup vs baseline: 1.2770x; 1.1747x over previous
//
#include <hip/hip_runtime.h>

#define T_N 256
#define O_N 64
#define K_N 16
#define HW_N (224 * 224)      // 50176
#define DM 768
#define DO 2048
#define OMEGA_F 1e-6f

typedef float f32x4 __attribute__((ext_vector_type(4)));

// ---- proj decomposition: column-tiles x K-segments, atomic split-K ----
#define PCOLS 64
#define DSEG 64                     // d's per proj block
#define NSEG (DM / DSEG)            // 12
#define NT_O (DO / PCOLS)           // 32 col-tiles (obj proj)
#define NT_F (DM / PCOLS)           // 12 col-tiles (frame proj)
#define NB_PROJ ((NT_O + NT_F) * NSEG)   // 528
#define SUBB 4
#define NB_HIST (T_N * SUBB)        // 1024
#define NB_OBJ (T_N * O_N / 4)      // 4096  (one wave per row, 4 rows/block)

// ============ K1: projection GEMMs via atomic split-K (proven R4 component)
__global__ __launch_bounds__(256) void proj_kernel(const float* __restrict__ me,
                                                   const float* __restrict__ Wo, const float* __restrict__ bo,
                                                   const float* __restrict__ Wf, const float* __restrict__ bf,
                                                   float* __restrict__ proj_obj, float* __restrict__ proj_frame) {
    __shared__ float partial[4][K_N][PCOLS];   // 16 KB
    __shared__ float me_s[K_N * DSEG];         // 4 KB
    const int b = blockIdx.x;
    const int tid = threadIdx.x;

    const int tile = b / NSEG, seg = b - tile * NSEG;
    const float* W; const float* bias; float* out; int ld; int j0;
    if (tile < NT_O) { W = Wo; bias = bo; out = proj_obj;   ld = DO; j0 = tile * PCOLS; }
    else             { W = Wf; bias = bf; out = proj_frame; ld = DM; j0 = (tile - NT_O) * PCOLS; }
    const int d0 = seg * DSEG;

    for (int i = tid; i < K_N * DSEG; i += 256) {
        int k = i >> 6, dd = i & 63;
        me_s[i] = me[k * DM + d0 + dd];
    }
    __syncthreads();

    const int jj = tid & (PCOLS - 1);
    const int s  = tid >> 6;            // wave id 0..3
    const int j  = j0 + jj;
    const int db = s * 16;

    float acc[K_N];
    #pragma unroll
    for (int k = 0; k < K_N; ++k) acc[k] = 0.f;

    #pragma unroll
    for (int dd = 0; dd < 16; ++dd) {
        float w = W[(size_t)(d0 + db + dd) * ld + j];      // coalesced
        #pragma unroll
        for (int k = 0; k < K_N; ++k)
            acc[k] += me_s[k * DSEG + db + dd] * w;        // LDS broadcast
    }
    #pragma unroll
    for (int k = 0; k < K_N; ++k) partial[s][k][jj] = acc[k];
    __syncthreads();

    for (int o = tid; o < K_N * PCOLS; o += 256) {
        int k = o >> 6, c = o & 63;
        float v = partial[0][k][c] + partial[1][k][c]
                + partial[2][k][c] + partial[3][k][c];
        if (seg == NSEG - 1) v += bias[j0 + c];
        atomicAdd(&out[k * ld + j0 + c], v);
    }
}

// ============ K2: histogram blocks [0..1023] + obj injection blocks [1024..5119]
// Independent streams (masks 51MB, obj 134+134MB) overlap in one dispatch.
// obj stores are nontemporal: obj_out is never re-read; keep L3 for the read streams.
__global__ __launch_bounds__(256) void objhist_kernel(const int* __restrict__ masks,
                                                      float* __restrict__ counts_partial,
                                                      const float* __restrict__ obj_feat,
                                                      const int* __restrict__ obj_entity,
                                                      const float* __restrict__ proj_obj,
                                                      const float* __restrict__ gamma,
                                                      float* __restrict__ obj_out) {
    __shared__ char smem[18496];
    const int b = blockIdx.x;
    const int tid = threadIdx.x;

    if (b < NB_HIST) {
        // ---- histogram: per-thread private bins, 4 sub-blocks per frame
        int* bins = (int*)smem;                                  // 256*17 ints
        int (*partial2)[17] = (int (*)[17])(smem + 256 * 17 * 4);
        const int t = b >> 2, sub = b & 3;
        int* my = &bins[tid * 17];
        #pragma unroll
        for (int i = 0; i < 17; ++i) my[i] = 0;

        const int4* p = (const int4*)(masks + (size_t)t * HW_N);
        const int n4 = HW_N / 4;          // 12544
        const int chunk = n4 / SUBB;      // 3136
        const int end = (sub + 1) * chunk;
        for (int i = sub * chunk + tid; i < end; i += 256) {
            int4 v = p[i];
            my[v.x]++; my[v.y]++; my[v.z]++; my[v.w]++;
        }
        __syncthreads();
        const int bcol = tid & 15, rg = tid >> 4;
        int ssum = 0;
        #pragma unroll
        for (int r = 0; r < 16; ++r) ssum += bins[(rg * 16 + r) * 17 + (bcol + 1)];
        partial2[rg][bcol] = ssum;
        __syncthreads();
        if (tid < 16) {
            int s = 0;
            #pragma unroll
            for (int r = 0; r < 16; ++r) s += partial2[r][tid];
            counts_partial[((size_t)sub * T_N + t) * K_N + tid] = (float)s;
        }
    } else {
        // ---- obj: wave w owns one 2048-float row; 64 lanes x 8 float4
        const int wave = tid >> 6;
        const int lane = tid & 63;
        const int row = (b - NB_HIST) * 4 + wave;
        const int e = obj_entity[row];              // wave-uniform
        const float g = gamma[0];
        const f32x4* __restrict__ src = (const f32x4*)(obj_feat + (size_t)row * DO);
        f32x4* __restrict__ dst = (f32x4*)(obj_out + (size_t)row * DO);
        if (e > 0) {                                // wave-uniform branch
            const f32x4* __restrict__ pr = (const f32x4*)(proj_obj + (size_t)(e - 1) * DO);
            f32x4 a[8], p[8];
            #pragma unroll
            for (int it = 0; it < 8; ++it) a[it] = src[lane + it * 64];
            #pragma unroll
            for (int it = 0; it < 8; ++it) p[it] = pr[lane + it * 64];
            #pragma unroll
            for (int it = 0; it < 8; ++it) {
                f32x4 r = a[it] + g * p[it];
                __builtin_nontemporal_store(r, &dst[lane + it * 64]);
            }
        } else {
            #pragma unroll
            for (int it = 0; it < 8; ++it) {
                f32x4 a = src[lane + it * 64];
                __builtin_nontemporal_store(a, &dst[lane + it * 64]);
            }
        }
    }
}

// ============ K3: frame injection (256 blocks)
__global__ __launch_bounds__(256) void frame_kernel(const float* __restrict__ frame_feat,
                                                    const float* __restrict__ counts_partial,
                                                    const float* __restrict__ proj_frame,
                                                    const float* __restrict__ gamma,
                                                    float* __restrict__ frame_out) {
    __shared__ float c[K_N];
    const int t = blockIdx.x;
    const float g = gamma[0];
    if (threadIdx.x < K_N) {
        float s = 0.f;
        #pragma unroll
        for (int sb = 0; sb < SUBB; ++sb)
            s += counts_partial[((size_t)sb * T_N + t) * K_N + threadIdx.x];
        c[threadIdx.x] = s;
    }
    __syncthreads();
    float tot = 0.f;
    #pragma unroll
    for (int k = 0; k < K_N; ++k) tot += c[k];
    const float inv = g / (OMEGA_F + tot);
    for (int j = threadIdx.x; j < DM; j += 256) {
        float acc = 0.f;
        #pragma unroll
        for (int k = 0; k < K_N; ++k) acc += c[k] * proj_frame[k * DM + j];
        frame_out[t * DM + j] = frame_feat[t * DM + j] + acc * inv;
    }
}

extern "C" void kernel_launch(void* const* d_in, const int* in_sizes, int n_in,
                              void* d_out, int out_size, void* d_ws, size_t ws_size,
                              hipStream_t stream) {
    const float* obj_feat   = (const float*)d_in[0];   // [T,O,DO]
    const float* frame_feat = (const float*)d_in[1];   // [T,DM]
    const float* me         = (const float*)d_in[2];   // [K,DM]
    const int*   obj_entity = (const int*)d_in[3];     // [T,O]
    const int*   masks      = (const int*)d_in[4];     // [T,H,W]
    const float* Wo         = (const float*)d_in[5];   // [DM,DO]
    const float* bo         = (const float*)d_in[6];   // [DO]
    const float* Wf         = (const float*)d_in[7];   // [DM,DM]
    const float* bf         = (const float*)d_in[8];   // [DM]
    const float* gamma      = (const float*)d_in[9];   // scalar

    float* obj_out   = (float*)d_out;                          // [T,O,DO]
    float* frame_out = (float*)d_out + (size_t)T_N * O_N * DO; // [T,DM]

    float* ws = (float*)d_ws;
    float* proj_obj       = ws;                  // 16*2048 = 32768 floats
    float* proj_frame     = ws + 32768;          // 16*768  = 12288 floats
    float* counts_partial = ws + 32768 + 12288;  // 4*256*16 = 16384 floats

    // zero the atomic split-K accumulators (capture-legal memset node)
    hipMemsetAsync(ws, 0, (size_t)(32768 + 12288) * sizeof(float), stream);

    // K1: projections (proj_obj needed by K2's obj path, proj_frame by K3)
    proj_kernel<<<NB_PROJ, 256, 0, stream>>>(me, Wo, bo, Wf, bf, proj_obj, proj_frame);
    // K2: independent hist + obj streams overlapped
    objhist_kernel<<<NB_HIST + NB_OBJ, 256, 0, stream>>>(
        masks, counts_partial, obj_feat, obj_entity, proj_obj, gamma, obj_out);
    // K3: frame injection (needs counts from K2)
    frame_kernel<<<T_N, 256, 0, stream>>>(frame_feat, counts_partial, proj_frame, gamma, frame_out);
}